// Round 1
// baseline (1504.976 us; speedup 1.0000x reference)
//
#include <hip/hip_runtime.h>

#define NFEAT 64

// ---------------- K0: detect whether edge_index is int64 or int32 ----------
// Reference declares jnp.int64; harness convention is int32. Values are
// < 50000 (17 bits), so under an int64 encoding every odd int32 word of the
// src region is 0. Probe 256 samples: all-zero => int64 (false-positive
// probability (2e-5)^256 ~ 0).
__global__ void k_detect(const int* __restrict__ ei, int* __restrict__ flag) {
    __shared__ int any_nonzero;
    if (threadIdx.x == 0) any_nonzero = 0;
    __syncthreads();
    if (ei[2 * threadIdx.x + 1] != 0) atomicOr(&any_nonzero, 1);
    __syncthreads();
    if (threadIdx.x == 0) flag[0] = any_nonzero ? 0 : 1;   // 1 => int64
}

__device__ __forceinline__ int load_idx(const int* __restrict__ ei, long long elem, int is64) {
    return is64 ? ei[2 * elem] : ei[elem];
}

// ---------------- K1: deg init (self loop counts 1) -------------------------
__global__ void k_deg_init(float* __restrict__ deg, int N) {
    int v = blockIdx.x * blockDim.x + threadIdx.x;
    if (v < N) deg[v] = 1.0f;
}

// ---------------- K2: in-degree over dst ------------------------------------
__global__ void k_deg(const int* __restrict__ ei, const int* __restrict__ flag,
                      float* __restrict__ deg, int E) {
    int i = blockIdx.x * blockDim.x + threadIdx.x;
    if (i >= E) return;
    int is64 = flag[0];
    int d = load_idx(ei, (long long)E + i, is64);
    atomicAdd(&deg[d], 1.0f);
}

// ---------------- K3: dinv = rsqrt(deg); agg = x/deg (self-loop message) ----
__global__ void k_node_init(const float* __restrict__ x, const float* __restrict__ deg,
                            float* __restrict__ dinv, float* __restrict__ agg, int N) {
    int t = blockIdx.x * blockDim.x + threadIdx.x;      // over N*16 float4s
    if (t >= N * 16) return;
    int v = t >> 4, p = t & 15;
    float dg = deg[v];
    float inv = 1.0f / dg;
    if (p == 0) dinv[v] = rsqrtf(dg);
    float4 xv = ((const float4*)x)[t];
    float4 o;
    o.x = xv.x * inv; o.y = xv.y * inv; o.z = xv.z * inv; o.w = xv.w * inv;
    ((float4*)agg)[t] = o;
    (void)p;
}

// ---------------- K4: edge scatter: agg[dst] += dinv[s]*dinv[d] * x[src] ----
// 16 threads per edge; each handles one float4 of the 64-wide feature row.
__global__ void k_scatter(const int* __restrict__ ei, const int* __restrict__ flag,
                          const float* __restrict__ x, const float* __restrict__ dinv,
                          float* __restrict__ agg, int E) {
    long long t = (long long)blockIdx.x * blockDim.x + threadIdx.x;
    if (t >= (long long)E * 16) return;
    int e = (int)(t >> 4);
    int p = (int)(t & 15);
    int is64 = flag[0];
    int s = load_idx(ei, e, is64);
    int d = load_idx(ei, (long long)E + e, is64);
    float norm = dinv[s] * dinv[d];
    float4 xv = ((const float4*)x)[s * 16 + p];
    float* base = agg + (long long)d * NFEAT + p * 4;
    atomicAdd(base + 0, norm * xv.x);
    atomicAdd(base + 1, norm * xv.y);
    atomicAdd(base + 2, norm * xv.z);
    atomicAdd(base + 3, norm * xv.w);
}

// ---------------- K5: out = relu((agg/deg)@W1) * sigmoid((agg/deg)@W2) ------
// 4 waves per block, one row per wave per iteration. W1,W2 staged in LDS
// (32 KiB -> 5 blocks/CU LDS cap, fine). Row element broadcast via __shfl.
__global__ __launch_bounds__(256) void k_out(const float* __restrict__ agg,
                                             const float* __restrict__ deg,
                                             const float* __restrict__ W1,
                                             const float* __restrict__ W2,
                                             float* __restrict__ out, int N) {
    __shared__ float w1[NFEAT * NFEAT];
    __shared__ float w2[NFEAT * NFEAT];
    for (int i = threadIdx.x; i < NFEAT * NFEAT; i += 256) {
        w1[i] = W1[i];
        w2[i] = W2[i];
    }
    __syncthreads();
    int wave = threadIdx.x >> 6;
    int lane = threadIdx.x & 63;
    for (int r = blockIdx.x * 4 + wave; r < N; r += gridDim.x * 4) {
        float inv = 1.0f / deg[r];
        float av = agg[r * NFEAT + lane] * inv;
        float acc1 = 0.0f, acc2 = 0.0f;
#pragma unroll
        for (int k = 0; k < NFEAT; ++k) {
            float ak = __shfl(av, k, 64);
            acc1 = fmaf(ak, w1[k * NFEAT + lane], acc1);
            acc2 = fmaf(ak, w2[k * NFEAT + lane], acc2);
        }
        float x1 = fmaxf(acc1, 0.0f);
        float x2 = 1.0f / (1.0f + __expf(-acc2));
        out[(long long)r * NFEAT + lane] = x1 * x2;
    }
}

extern "C" void kernel_launch(void* const* d_in, const int* in_sizes, int n_in,
                              void* d_out, int out_size, void* d_ws, size_t ws_size,
                              hipStream_t stream) {
    const float* x  = (const float*)d_in[0];
    const int*   ei = (const int*)d_in[1];
    const float* W1 = (const float*)d_in[2];
    const float* W2 = (const float*)d_in[3];
    float* out = (float*)d_out;

    const int N = in_sizes[0] / NFEAT;       // 50000
    const int E = in_sizes[1] / 2;           // 1,600,000

    // workspace layout (16B-aligned slices)
    char* ws = (char*)d_ws;
    int*   flag = (int*)ws;                                  // 256 B reserved
    float* deg  = (float*)(ws + 256);                        // N floats
    size_t degb = ((size_t)N * 4 + 255) & ~(size_t)255;
    float* dinv = (float*)(ws + 256 + degb);                 // N floats
    float* agg  = (float*)(ws + 256 + 2 * degb);             // N*64 floats

    k_detect<<<1, 256, 0, stream>>>(ei, flag);
    k_deg_init<<<(N + 255) / 256, 256, 0, stream>>>(deg, N);
    k_deg<<<(E + 255) / 256, 256, 0, stream>>>(ei, flag, deg, E);
    k_node_init<<<(N * 16 + 255) / 256, 256, 0, stream>>>(x, deg, dinv, agg, N);
    long long scatter_items = (long long)E * 16;
    int scatter_blocks = (int)((scatter_items + 255) / 256);
    k_scatter<<<scatter_blocks, 256, 0, stream>>>(ei, flag, x, dinv, agg, E);
    k_out<<<2048, 256, 0, stream>>>(agg, deg, W1, W2, out, N);
}

// Round 2
// 468.716 us; speedup vs baseline: 3.2108x; 3.2108x over previous
//
#include <hip/hip_runtime.h>

#define NFEAT 64

// ---------------- K0: detect whether edge_index is int64 or int32 ----------
// Values < 50000 (17 bits): under int64 encoding every odd int32 word is 0.
__global__ void k_detect(const int* __restrict__ ei, int* __restrict__ flag) {
    __shared__ int any_nonzero;
    if (threadIdx.x == 0) any_nonzero = 0;
    __syncthreads();
    if (ei[2 * threadIdx.x + 1] != 0) atomicOr(&any_nonzero, 1);
    __syncthreads();
    if (threadIdx.x == 0) flag[0] = any_nonzero ? 0 : 1;   // 1 => int64
}

__device__ __forceinline__ int load_idx(const int* __restrict__ ei, long long elem, int is64) {
    return is64 ? ei[2 * elem] : ei[(int)elem];
}

// ---------------- zero int array -------------------------------------------
__global__ void k_zero(int* __restrict__ p, int n) {
    int i = blockIdx.x * blockDim.x + threadIdx.x;
    if (i < n) p[i] = 0;
}

// ---------------- histogram of dst (real edges only) ------------------------
__global__ void k_hist(const int* __restrict__ ei, const int* __restrict__ flag,
                       int* __restrict__ count, int E) {
    int i = blockIdx.x * blockDim.x + threadIdx.x;
    if (i >= E) return;
    int is64 = flag[0];
    int d = load_idx(ei, (long long)E + i, is64);
    atomicAdd(&count[d], 1);
}

// ---------------- deg = count+1 (self loop), dinv = rsqrt(deg) ---------------
__global__ void k_finalize(const int* __restrict__ count, float* __restrict__ deg,
                           float* __restrict__ dinv, int N) {
    int v = blockIdx.x * blockDim.x + threadIdx.x;
    if (v >= N) return;
    float dg = (float)(count[v] + 1);
    deg[v] = dg;
    dinv[v] = rsqrtf(dg);
}

// ---------------- scan stage 1: per-block sums of count ---------------------
__global__ void k_bsum(const int* __restrict__ count, int* __restrict__ bsum, int N) {
    __shared__ int s[256];
    int i = blockIdx.x * 256 + threadIdx.x;
    s[threadIdx.x] = (i < N) ? count[i] : 0;
    __syncthreads();
    for (int off = 128; off > 0; off >>= 1) {
        if (threadIdx.x < off) s[threadIdx.x] += s[threadIdx.x + off];
        __syncthreads();
    }
    if (threadIdx.x == 0) bsum[blockIdx.x] = s[0];
}

// ---------------- scan stage 2: exclusive scan of block sums (single block) --
__global__ void k_bscan(const int* __restrict__ bsum, int* __restrict__ bpre, int NB) {
    __shared__ int s[1024];
    int t = threadIdx.x;
    int mine = (t < NB) ? bsum[t] : 0;
    s[t] = mine;
    __syncthreads();
    for (int off = 1; off < 1024; off <<= 1) {
        int v = (t >= off) ? s[t - off] : 0;
        __syncthreads();
        s[t] += v;
        __syncthreads();
    }
    if (t < NB) bpre[t] = s[t] - mine;   // exclusive prefix
}

// ---------------- scan stage 3: ptr/fill = global exclusive scan ------------
__global__ void k_ptr(const int* __restrict__ count, const int* __restrict__ bpre,
                      int* __restrict__ ptr, int* __restrict__ fill, int N) {
    __shared__ int s[256];
    int i = blockIdx.x * 256 + threadIdx.x;
    int c = (i < N) ? count[i] : 0;
    s[threadIdx.x] = c;
    __syncthreads();
    for (int off = 1; off < 256; off <<= 1) {
        int v = (threadIdx.x >= off) ? s[threadIdx.x - off] : 0;
        __syncthreads();
        s[threadIdx.x] += v;
        __syncthreads();
    }
    if (i < N) {
        int excl = bpre[blockIdx.x] + s[threadIdx.x] - c;
        ptr[i] = excl;
        fill[i] = excl;
    }
}

// ---------------- fill CSR: sorted_src[pos] = src ----------------------------
__global__ void k_fill(const int* __restrict__ ei, const int* __restrict__ flag,
                       int* __restrict__ fill, int* __restrict__ sorted_src, int E) {
    int i = blockIdx.x * blockDim.x + threadIdx.x;
    if (i >= E) return;
    int is64 = flag[0];
    int s = load_idx(ei, i, is64);
    int d = load_idx(ei, (long long)E + i, is64);
    int pos = atomicAdd(&fill[d], 1);
    sorted_src[pos] = s;
}

// ---------------- gather + fused dual-GEMM epilogue --------------------------
// One wave per node; lane = feature index. Edge srcs preloaded 64 at a time
// (coalesced), broadcast via shfl; x-row reads are 256B coalesced per edge.
// Epilogue: out = relu(a@W1) * sigmoid(a@W2), W1/W2 staged in LDS.
__global__ __launch_bounds__(256) void k_gather_out(
        const float* __restrict__ x, const float* __restrict__ deg,
        const float* __restrict__ dinv, const int* __restrict__ ptr,
        const int* __restrict__ count, const int* __restrict__ sorted_src,
        const float* __restrict__ W1, const float* __restrict__ W2,
        float* __restrict__ out, int N) {
    __shared__ float w1[NFEAT * NFEAT];
    __shared__ float w2[NFEAT * NFEAT];
    for (int i = threadIdx.x; i < NFEAT * NFEAT; i += 256) {
        w1[i] = W1[i];
        w2[i] = W2[i];
    }
    __syncthreads();
    int wave = threadIdx.x >> 6;
    int lane = threadIdx.x & 63;

    for (int v = blockIdx.x * 4 + wave; v < N; v += gridDim.x * 4) {
        float invdeg = 1.0f / deg[v];
        float dv = dinv[v];
        int start = ptr[v];
        int cnt = count[v];
        // self-loop message: x[v]/deg
        float acc = x[(size_t)v * NFEAT + lane] * invdeg;
        for (int c = 0; c < cnt; c += 64) {
            int m = min(64, cnt - c);
            int s_l = 0;
            float w_l = 0.0f;
            if (lane < m) {
                s_l = sorted_src[start + c + lane];
                w_l = dinv[s_l];
            }
            for (int j = 0; j < m; ++j) {
                int s = __shfl(s_l, j, 64);
                float w = __shfl(w_l, j, 64);
                acc = fmaf(w * dv, x[(size_t)s * NFEAT + lane], acc);
            }
        }
        acc *= invdeg;   // mean aggregation

        // dual GEMM: row 'acc' (one element per lane) against W1/W2
        float acc1 = 0.0f, acc2 = 0.0f;
#pragma unroll
        for (int k = 0; k < NFEAT; ++k) {
            float ak = __shfl(acc, k, 64);
            acc1 = fmaf(ak, w1[k * NFEAT + lane], acc1);
            acc2 = fmaf(ak, w2[k * NFEAT + lane], acc2);
        }
        float x1 = fmaxf(acc1, 0.0f);
        float x2 = 1.0f / (1.0f + __expf(-acc2));
        out[(size_t)v * NFEAT + lane] = x1 * x2;
    }
}

extern "C" void kernel_launch(void* const* d_in, const int* in_sizes, int n_in,
                              void* d_out, int out_size, void* d_ws, size_t ws_size,
                              hipStream_t stream) {
    const float* x  = (const float*)d_in[0];
    const int*   ei = (const int*)d_in[1];
    const float* W1 = (const float*)d_in[2];
    const float* W2 = (const float*)d_in[3];
    float* out = (float*)d_out;

    const int N = in_sizes[0] / NFEAT;       // 50000
    const int E = in_sizes[1] / 2;           // 1,600,000
    const int NB = (N + 255) / 256;          // scan blocks (196)

    // workspace layout (256B-aligned slices)
    char* ws = (char*)d_ws;
    size_t off = 0;
    auto alloc = [&](size_t bytes) {
        char* p = ws + off;
        off = (off + bytes + 255) & ~(size_t)255;
        return p;
    };
    int*   flag       = (int*)alloc(256);
    int*   count      = (int*)alloc((size_t)N * 4);
    float* deg        = (float*)alloc((size_t)N * 4);
    float* dinv       = (float*)alloc((size_t)N * 4);
    int*   ptr        = (int*)alloc((size_t)N * 4);
    int*   fill       = (int*)alloc((size_t)N * 4);
    int*   bsum       = (int*)alloc((size_t)NB * 4);
    int*   bpre       = (int*)alloc((size_t)NB * 4);
    int*   sorted_src = (int*)alloc((size_t)E * 4);

    k_detect<<<1, 256, 0, stream>>>(ei, flag);
    k_zero<<<(N + 255) / 256, 256, 0, stream>>>(count, N);
    k_hist<<<(E + 255) / 256, 256, 0, stream>>>(ei, flag, count, E);
    k_finalize<<<(N + 255) / 256, 256, 0, stream>>>(count, deg, dinv, N);
    k_bsum<<<NB, 256, 0, stream>>>(count, bsum, N);
    k_bscan<<<1, 1024, 0, stream>>>(bsum, bpre, NB);
    k_ptr<<<NB, 256, 0, stream>>>(count, bpre, ptr, fill, N);
    k_fill<<<(E + 255) / 256, 256, 0, stream>>>(ei, flag, fill, sorted_src, E);
    k_gather_out<<<(N + 3) / 4, 256, 0, stream>>>(x, deg, dinv, ptr, count,
                                                  sorted_src, W1, W2, out, N);
}

// Round 3
// 396.454 us; speedup vs baseline: 3.7961x; 1.1823x over previous
//
#include <hip/hip_runtime.h>

#define NFEAT 64

// ---------------- K0: detect whether edge_index is int64 or int32 ----------
// Values < 50000 (17 bits): under int64 encoding every odd int32 word is 0.
__global__ void k_detect(const int* __restrict__ ei, int* __restrict__ flag) {
    __shared__ int any_nonzero;
    if (threadIdx.x == 0) any_nonzero = 0;
    __syncthreads();
    if (ei[2 * threadIdx.x + 1] != 0) atomicOr(&any_nonzero, 1);
    __syncthreads();
    if (threadIdx.x == 0) flag[0] = any_nonzero ? 0 : 1;   // 1 => int64
}

__device__ __forceinline__ int load_idx(const int* __restrict__ ei, long long elem, int is64) {
    return is64 ? ei[2 * elem] : ei[(int)elem];
}

// ---------------- histogram of dst (real edges only) ------------------------
__global__ void k_hist(const int* __restrict__ ei, const int* __restrict__ flag,
                       int* __restrict__ count, int E) {
    int i = blockIdx.x * blockDim.x + threadIdx.x;
    if (i >= E) return;
    int is64 = flag[0];
    int d = load_idx(ei, (long long)E + i, is64);
    atomicAdd(&count[d], 1);
}

// ------- deg-derived per-node factors + y = dinv * x (one float4/thread) ----
__global__ void k_finalize(const int* __restrict__ count, const float* __restrict__ x,
                           float* __restrict__ dinv, float* __restrict__ scale,
                           float* __restrict__ y, int N, int make_y) {
    int t = blockIdx.x * blockDim.x + threadIdx.x;   // over N*16 float4s
    if (t >= N * 16) return;
    int v = t >> 4;
    float dg = (float)(count[v] + 1);                // +1 self loop
    float dv = rsqrtf(dg);
    if ((t & 15) == 0) {
        dinv[v] = dv;
        scale[v] = dv / dg;                          // dinv[v]/deg[v]
    }
    if (make_y) {
        float4 xv = ((const float4*)x)[t];
        float4 o;
        o.x = xv.x * dv; o.y = xv.y * dv; o.z = xv.z * dv; o.w = xv.w * dv;
        ((float4*)y)[t] = o;
    }
}

// ---------------- scan stage 1: per-block sums of count ---------------------
__global__ void k_bsum(const int* __restrict__ count, int* __restrict__ bsum, int N) {
    __shared__ int s[256];
    int i = blockIdx.x * 256 + threadIdx.x;
    s[threadIdx.x] = (i < N) ? count[i] : 0;
    __syncthreads();
    for (int off = 128; off > 0; off >>= 1) {
        if (threadIdx.x < off) s[threadIdx.x] += s[threadIdx.x + off];
        __syncthreads();
    }
    if (threadIdx.x == 0) bsum[blockIdx.x] = s[0];
}

// ---------------- scan stage 2: exclusive scan of block sums (single block) --
__global__ void k_bscan(const int* __restrict__ bsum, int* __restrict__ bpre, int NB) {
    __shared__ int s[1024];
    int t = threadIdx.x;
    int mine = (t < NB) ? bsum[t] : 0;
    s[t] = mine;
    __syncthreads();
    for (int off = 1; off < 1024; off <<= 1) {
        int v = (t >= off) ? s[t - off] : 0;
        __syncthreads();
        s[t] += v;
        __syncthreads();
    }
    if (t < NB) bpre[t] = s[t] - mine;   // exclusive prefix
}

// ---------------- scan stage 3: ptr/fill = global exclusive scan ------------
__global__ void k_ptr(const int* __restrict__ count, const int* __restrict__ bpre,
                      int* __restrict__ ptr, int* __restrict__ fill, int N) {
    __shared__ int s[256];
    int i = blockIdx.x * 256 + threadIdx.x;
    int c = (i < N) ? count[i] : 0;
    s[threadIdx.x] = c;
    __syncthreads();
    for (int off = 1; off < 256; off <<= 1) {
        int v = (threadIdx.x >= off) ? s[threadIdx.x - off] : 0;
        __syncthreads();
        s[threadIdx.x] += v;
        __syncthreads();
    }
    if (i < N) {
        int excl = bpre[blockIdx.x] + s[threadIdx.x] - c;
        ptr[i] = excl;
        fill[i] = excl;
    }
}

// ---------------- fill CSR: sorted_src[pos] = src ----------------------------
__global__ void k_fill(const int* __restrict__ ei, const int* __restrict__ flag,
                       int* __restrict__ fill, int* __restrict__ sorted_src, int E) {
    int i = blockIdx.x * blockDim.x + threadIdx.x;
    if (i >= E) return;
    int is64 = flag[0];
    int s = load_idx(ei, i, is64);
    int d = load_idx(ei, (long long)E + i, is64);
    int pos = atomicAdd(&fill[d], 1);
    sorted_src[pos] = s;
}

// ---------------- gather (8 independent chains) + fused dual-GEMM epilogue ---
// USE_Y: xy = y = dinv*x (pure load+add per edge). Else xy = x and per-edge
// weight dinv[s] is gathered with the src batch and shfl-broadcast.
template <bool USE_Y>
__global__ __launch_bounds__(256) void k_gather_out(
        const float* __restrict__ xy, const float* __restrict__ dinv,
        const float* __restrict__ scale, const int* __restrict__ ptr,
        const int* __restrict__ count, const int* __restrict__ sorted_src,
        const float* __restrict__ W1, const float* __restrict__ W2,
        float* __restrict__ out, int N) {
    __shared__ float w1[NFEAT * NFEAT];
    __shared__ float w2[NFEAT * NFEAT];
    for (int i = threadIdx.x; i < NFEAT * NFEAT; i += 256) {
        w1[i] = W1[i];
        w2[i] = W2[i];
    }
    __syncthreads();
    int wave = threadIdx.x >> 6;
    int lane = threadIdx.x & 63;

    for (int v = blockIdx.x * 4 + wave; v < N; v += gridDim.x * 4) {
        int start = ptr[v];
        int cnt = count[v];
        float dv = dinv[v];
        float sc = scale[v];
        // self-loop term: y[v] (= dv*x[v])
        float a0 = USE_Y ? xy[(size_t)v * NFEAT + lane]
                         : xy[(size_t)v * NFEAT + lane] * dv;
        float a1 = 0.f, a2 = 0.f, a3 = 0.f, a4 = 0.f, a5 = 0.f, a6 = 0.f, a7 = 0.f;

        for (int c = 0; c < cnt; c += 64) {
            int m = min(64, cnt - c);
            int s_l = 0;
            float w_l = 0.f;
            if (lane < m) {
                s_l = sorted_src[start + c + lane];
                if (!USE_Y) w_l = dinv[s_l];
            }
            int j = 0;
            for (; j + 8 <= m; j += 8) {
                int s0 = __shfl(s_l, j + 0, 64), s1 = __shfl(s_l, j + 1, 64);
                int s2 = __shfl(s_l, j + 2, 64), s3 = __shfl(s_l, j + 3, 64);
                int s4 = __shfl(s_l, j + 4, 64), s5 = __shfl(s_l, j + 5, 64);
                int s6 = __shfl(s_l, j + 6, 64), s7 = __shfl(s_l, j + 7, 64);
                if (USE_Y) {
                    a0 += xy[(size_t)s0 * NFEAT + lane];
                    a1 += xy[(size_t)s1 * NFEAT + lane];
                    a2 += xy[(size_t)s2 * NFEAT + lane];
                    a3 += xy[(size_t)s3 * NFEAT + lane];
                    a4 += xy[(size_t)s4 * NFEAT + lane];
                    a5 += xy[(size_t)s5 * NFEAT + lane];
                    a6 += xy[(size_t)s6 * NFEAT + lane];
                    a7 += xy[(size_t)s7 * NFEAT + lane];
                } else {
                    float w0 = __shfl(w_l, j + 0, 64), w1f = __shfl(w_l, j + 1, 64);
                    float w2f = __shfl(w_l, j + 2, 64), w3 = __shfl(w_l, j + 3, 64);
                    float w4 = __shfl(w_l, j + 4, 64), w5 = __shfl(w_l, j + 5, 64);
                    float w6 = __shfl(w_l, j + 6, 64), w7 = __shfl(w_l, j + 7, 64);
                    a0 = fmaf(w0, xy[(size_t)s0 * NFEAT + lane], a0);
                    a1 = fmaf(w1f, xy[(size_t)s1 * NFEAT + lane], a1);
                    a2 = fmaf(w2f, xy[(size_t)s2 * NFEAT + lane], a2);
                    a3 = fmaf(w3, xy[(size_t)s3 * NFEAT + lane], a3);
                    a4 = fmaf(w4, xy[(size_t)s4 * NFEAT + lane], a4);
                    a5 = fmaf(w5, xy[(size_t)s5 * NFEAT + lane], a5);
                    a6 = fmaf(w6, xy[(size_t)s6 * NFEAT + lane], a6);
                    a7 = fmaf(w7, xy[(size_t)s7 * NFEAT + lane], a7);
                }
            }
            for (; j < m; ++j) {
                int s0 = __shfl(s_l, j, 64);
                if (USE_Y) {
                    a0 += xy[(size_t)s0 * NFEAT + lane];
                } else {
                    float w0 = __shfl(w_l, j, 64);
                    a0 = fmaf(w0, xy[(size_t)s0 * NFEAT + lane], a0);
                }
            }
        }
        float a = ((a0 + a1) + (a2 + a3)) + ((a4 + a5) + (a6 + a7));
        a *= sc;   // * dinv[v] / deg[v]

        // dual GEMM: row 'a' (one element per lane) against W1/W2
        float acc1 = 0.0f, acc2 = 0.0f;
#pragma unroll
        for (int k = 0; k < NFEAT; ++k) {
            float ak = __shfl(a, k, 64);
            acc1 = fmaf(ak, w1[k * NFEAT + lane], acc1);
            acc2 = fmaf(ak, w2[k * NFEAT + lane], acc2);
        }
        float x1 = fmaxf(acc1, 0.0f);
        float x2 = 1.0f / (1.0f + __expf(-acc2));
        out[(size_t)v * NFEAT + lane] = x1 * x2;
    }
}

extern "C" void kernel_launch(void* const* d_in, const int* in_sizes, int n_in,
                              void* d_out, int out_size, void* d_ws, size_t ws_size,
                              hipStream_t stream) {
    const float* x  = (const float*)d_in[0];
    const int*   ei = (const int*)d_in[1];
    const float* W1 = (const float*)d_in[2];
    const float* W2 = (const float*)d_in[3];
    float* out = (float*)d_out;

    const int N = in_sizes[0] / NFEAT;       // 50000
    const int E = in_sizes[1] / 2;           // 1,600,000
    const int NB = (N + 255) / 256;          // scan blocks

    // workspace layout (256B-aligned slices)
    char* ws = (char*)d_ws;
    size_t off = 0;
    auto alloc = [&](size_t bytes) {
        char* p = ws + off;
        off = (off + bytes + 255) & ~(size_t)255;
        return p;
    };
    int*   flag       = (int*)alloc(256);
    int*   count      = (int*)alloc((size_t)N * 4);
    float* dinv       = (float*)alloc((size_t)N * 4);
    float* scale      = (float*)alloc((size_t)N * 4);
    int*   ptr        = (int*)alloc((size_t)N * 4);
    int*   fill       = (int*)alloc((size_t)N * 4);
    int*   bsum       = (int*)alloc((size_t)NB * 4);
    int*   bpre       = (int*)alloc((size_t)NB * 4);
    int*   sorted_src = (int*)alloc((size_t)E * 4);
    size_t need_y = off + (size_t)N * NFEAT * 4;
    int use_y = (ws_size >= need_y) ? 1 : 0;
    float* y = (float*)alloc((size_t)N * NFEAT * 4);   // only touched if use_y

    k_detect<<<1, 256, 0, stream>>>(ei, flag);
    hipMemsetAsync(count, 0, (size_t)N * 4, stream);
    k_hist<<<(E + 255) / 256, 256, 0, stream>>>(ei, flag, count, E);
    k_finalize<<<(N * 16 + 255) / 256, 256, 0, stream>>>(count, x, dinv, scale, y, N, use_y);
    k_bsum<<<NB, 256, 0, stream>>>(count, bsum, N);
    k_bscan<<<1, 1024, 0, stream>>>(bsum, bpre, NB);
    k_ptr<<<NB, 256, 0, stream>>>(count, bpre, ptr, fill, N);
    k_fill<<<(E + 255) / 256, 256, 0, stream>>>(ei, flag, fill, sorted_src, E);
    if (use_y) {
        k_gather_out<true><<<(N + 3) / 4, 256, 0, stream>>>(
            y, dinv, scale, ptr, count, sorted_src, W1, W2, out, N);
    } else {
        k_gather_out<false><<<(N + 3) / 4, 256, 0, stream>>>(
            x, dinv, scale, ptr, count, sorted_src, W1, W2, out, N);
    }
}